// Round 3
// baseline (1126.235 us; speedup 1.0000x reference)
//
#include <hip/hip_runtime.h>
#include <hip/hip_bf16.h>
#include <cstdint>
#include <cfloat>
#include <math.h>

// Problem constants (fixed by the reference)
#define NN 4096      // rows
#define DD 256       // embedding dim
#define NNEG 4092    // negatives per row
#define MARGIN 0.5f
#define GTOTAL ((uint32_t)NN * (uint32_t)NNEG)  // 16,760,832 gumbel entries

// ---------------------------------------------------------------------------
// JAX threefry2x32, key = jax.random.key(42) -> (0, 42). Partitionable mode:
// counter (hi=0, lo=i), bits = o0 ^ o1. (verified bit-exact: absmax 0.0)
// ---------------------------------------------------------------------------
__device__ __forceinline__ uint32_t rotl32(uint32_t x, int r) {
  return (x << r) | (x >> (32 - r));
}

__device__ __forceinline__ void threefry2x32_42(uint32_t x0, uint32_t x1,
                                                uint32_t& o0, uint32_t& o1) {
  const uint32_t k0 = 0u, k1 = 42u;
  const uint32_t k2 = k0 ^ k1 ^ 0x1BD11BDAu;
  x0 += k0; x1 += k1;
#define TF_R(r) { x0 += x1; x1 = rotl32(x1, r); x1 ^= x0; }
  TF_R(13) TF_R(15) TF_R(26) TF_R(6)
  x0 += k1; x1 += k2 + 1u;
  TF_R(17) TF_R(29) TF_R(16) TF_R(24)
  x0 += k2; x1 += k0 + 2u;
  TF_R(13) TF_R(15) TF_R(26) TF_R(6)
  x0 += k0; x1 += k1 + 3u;
  TF_R(17) TF_R(29) TF_R(16) TF_R(24)
  x0 += k1; x1 += k2 + 4u;
  TF_R(13) TF_R(15) TF_R(26) TF_R(6)
  x0 += k2; x1 += k0 + 5u;
#undef TF_R
  o0 = x0; o1 = x1;
}

__device__ __forceinline__ float gumbel_at(uint32_t f) {
  uint32_t o0, o1;
  threefry2x32_42(0u, f, o0, o1);
  uint32_t bits = o0 ^ o1;
  uint32_t fb = (bits >> 9) | 0x3F800000u;
  float fl = __uint_as_float(fb) - 1.0f;
  float u = fmaxf(1e-20f, fl + 1e-20f);
  return -logf(-logf(u));   // libm logf kept: bit-exact anchor (absmax 0.0)
}

// Monotone bucket map over [-0.28, 0.28] (sims ~N(0, 1/256)); within-bucket
// order resolved by exact-value scan, so mapping affects speed only.
#define NB 4096
#define NW (NB / 2)
__device__ __forceinline__ int bucket_of(float v) {
  return (int)fminf(fmaxf((v + 0.28f) * 7314.2857f, 0.0f), (float)(NB - 1));
}

// ---------------------------------------------------------------------------
// GEMM v3 (R7): scalar-broadcast A. Block = 64 rows x 256 cols, one col per
// thread, acc[64]. B staged in LDS (1 ds_read_b128 / thread / k4); A read
// via wave-uniform pointers -> s_load_dwordx4 (SMEM pipe), removing the
// dominant LDS traffic (R5/R6 were LDS-BW-bound at ~150us; FMA floor ~29us).
// Per-element k accumulation order unchanged (kb asc, k4 asc, xyzw)
// -> sims bit-exact. Upper-triangle cover: tile (bi,bj) included iff
// bi <= 4*bj+3; every S element gets its bit-exact value via direct or
// transpose store (products commute termwise, same order).
// ---------------------------------------------------------------------------
#define RT 64                  // rows per tile
#define CT 256                 // cols per tile (one per thread)
#define GBK 32                 // k-chunk
#define BKP 36                 // Bs stride in dwords (144B, 16B-aligned)
#define TRI_BLOCKS 544         // sum_{bj=0..15} (4*bj+4)
#define GUMBEL_BLOCKS 256

template <int GOFF>
__global__ __launch_bounds__(256) void gemm_gumbel(const float* __restrict__ X,
                                                   float* __restrict__ S,
                                                   float* __restrict__ G) {
  __shared__ float Bs[CT * BKP];   // 36 KB
  const int tid = threadIdx.x;

  if (GOFF > 0 && (int)blockIdx.x < GOFF) {
    // Gumbel table fill: pure-VALU grid-stride stream, coalesced writes.
    uint32_t i = (uint32_t)blockIdx.x * 256u + (uint32_t)tid;
    const uint32_t stride = (uint32_t)GOFF * 256u;
    for (; i < GTOTAL; i += stride) G[i] = gumbel_at(i);
    return;
  }

  // decode linear tile index: prefix(bj) = 2*bj*(bj+1); bi = L - prefix
  int L = (int)blockIdx.x - GOFF;
  int bj = 0;
  while (L >= 2 * (bj + 1) * (bj + 2)) bj++;
  const int bi = L - 2 * bj * (bj + 1);
  const int rowBase = bi * RT, colBase = bj * CT;

  const int col = tid;
  const float* __restrict__ Xc = X + (size_t)(colBase + col) * DD;
  const float* __restrict__ Xa = X + (size_t)rowBase * DD;   // wave-uniform

  float acc[RT];
#pragma unroll
  for (int r = 0; r < RT; ++r) acc[r] = 0.0f;

  for (int kb = 0; kb < DD; kb += GBK) {
#pragma unroll
    for (int q = 0; q < GBK / 4; ++q) {
      float4 bv = *(const float4*)(Xc + kb + 4 * q);
      *(float4*)(&Bs[col * BKP + 4 * q]) = bv;
    }
    __syncthreads();
#pragma unroll
    for (int kk = 0; kk < GBK; kk += 4) {
      float4 bv = *(const float4*)(&Bs[col * BKP + kk]);
#pragma unroll
      for (int r = 0; r < RT; ++r) {
        float4 av = *(const float4*)(Xa + r * DD + kb + kk);  // uniform -> s_load
        acc[r] += av.x * bv.x;
        acc[r] += av.y * bv.y;
        acc[r] += av.z * bv.z;
        acc[r] += av.w * bv.w;
      }
    }
    __syncthreads();
  }

  // direct store: S[rowBase+r][colBase+col] (wave-coalesced 1KB per r)
#pragma unroll
  for (int r = 0; r < RT; ++r)
    S[(size_t)(rowBase + r) * NN + colBase + col] = acc[r];
  // transpose store: per-thread contiguous 256B runs (b128)
#pragma unroll
  for (int r = 0; r < RT; r += 4) {
    float4 t;
    t.x = acc[r]; t.y = acc[r + 1]; t.z = acc[r + 2]; t.w = acc[r + 3];
    *(float4*)(S + (size_t)(colBase + col) * NN + rowBase + r) = t;
  }
}

// ---------------------------------------------------------------------------
// Per-row kernel v7: 1024 threads/block (16 waves) -> occupancy cap 10 -> 32
// waves/CU; bucket-major rank phase (thread owns buckets tid+1024m) with
// wave-contiguous G loads; 4 elements/thread everywhere else.
// ---------------------------------------------------------------------------
#define INSERT3(sc, v)                                              \
  if ((sc) > s2) {                                                  \
    if ((sc) > s1) {                                                \
      s2 = s1; v2 = v1;                                             \
      if ((sc) > s0) { s1 = s0; v1 = v0; s0 = (sc); v0 = (v); }     \
      else           { s1 = (sc); v1 = (v); }                       \
    } else { s2 = (sc); v2 = (v); }                                 \
  }

template <int USE_G>
__global__ __launch_bounds__(1024) void row_kernel(const float* __restrict__ S,
                                                   const float* __restrict__ G,
                                                   float* __restrict__ acc) {
  __shared__ uint32_t histw[NW];            // 2x16-bit counts per word
  __shared__ uint32_t offsw[NW];            // 2x16-bit cursors -> bucket ends
  __shared__ __align__(16) float sval[NN];  // values scattered by bucket
  __shared__ float sh[160];  // 0..2 pos sorted, 3 mu, 4 inv2s2, 9 neg sum,
                             // 16..19 raw pos, 32..47 mean partials,
                             // 48..63 var partials, 64..159 wave top-3
  __shared__ uint32_t wtot[16];

  const int row = blockIdx.x;
  const int tid = threadIdx.x;
  const int lane = tid & 63, wid = tid >> 6;

  // zero histogram: 2 words/thread, stride 1024 -> conflict-free
  histw[tid] = 0u;
  histw[tid + 1024] = 0u;

  // load 4 elements (one coalesced float4/thread), capture + poison positives
  const float4* src = (const float4*)(S + (size_t)row * NN);
  const int pslot = row >> 2;
  float4 t4 = src[tid];
  if (tid == pslot) {
    sh[16] = t4.x; sh[17] = t4.y; sh[18] = t4.z; sh[19] = t4.w;
    t4.x = INFINITY; t4.y = INFINITY; t4.z = INFINITY; t4.w = INFINITY;
  }
  float vv[4];
  vv[0] = t4.x; vv[1] = t4.y; vv[2] = t4.z; vv[3] = t4.w;

  // mean partial sums (skip infs)
  float s = 0.0f;
#pragma unroll
  for (int e = 0; e < 4; ++e) if (vv[e] < 1e30f) s += vv[e];
#pragma unroll
  for (int off = 32; off > 0; off >>= 1) s += __shfl_down(s, off, 64);
  if (lane == 0) sh[32 + wid] = s;
  __syncthreads();   // B1: hist zeroed, mean partials, raw pos visible

  // histogram (packed halves; counts <= 4096 so no carry between halves)
#pragma unroll
  for (int e = 0; e < 4; ++e) {
    int b = bucket_of(vv[e]);
    atomicAdd(&histw[b >> 1], 1u << ((b & 1) << 4));
  }
  if (tid == 0) {
    int self = row & 3;
    float p[3]; int m = 0;
#pragma unroll
    for (int c = 0; c < 4; ++c)
      if (c != self) p[m++] = sh[16 + c];
    float t;
    if (p[0] > p[1]) { t = p[0]; p[0] = p[1]; p[1] = t; }
    if (p[1] > p[2]) { t = p[1]; p[1] = p[2]; p[2] = t; }
    if (p[0] > p[1]) { t = p[0]; p[0] = p[1]; p[1] = t; }
    sh[0] = p[0]; sh[1] = p[1]; sh[2] = p[2];
    float tot = 0.0f;
#pragma unroll
    for (int w = 0; w < 16; ++w) tot += sh[32 + w];
    sh[9] = tot;
    sh[3] = tot / (float)NNEG;
  }
  __syncthreads();   // B2: hist complete, mu visible

  // block exclusive prefix over NB buckets (4 buckets = 2 words per thread)
  uint32_t hw0 = histw[2 * tid], hw1 = histw[2 * tid + 1];
  uint32_t s4 = (hw0 & 0xFFFFu) + (hw0 >> 16) + (hw1 & 0xFFFFu) + (hw1 >> 16);
  uint32_t inc = s4;
#pragma unroll
  for (int off = 1; off < 64; off <<= 1) {
    uint32_t n = __shfl_up(inc, (unsigned)off, 64);
    if (lane >= off) inc += n;
  }
  if (lane == 63) wtot[wid] = inc;

  // variance partial sums (two-pass; mu from B2)
  const float mu = sh[3];
  float q = 0.0f;
#pragma unroll
  for (int e = 0; e < 4; ++e)
    if (vv[e] < 1e30f) { float d = vv[e] - mu; q += d * d; }
#pragma unroll
  for (int off = 32; off > 0; off >>= 1) q += __shfl_down(q, off, 64);
  if (lane == 0) sh[48 + wid] = q;
  __syncthreads();   // B3: wtot + var partials visible

  uint32_t wbase = 0;
  for (int w = 0; w < wid; ++w) wbase += wtot[w];
  uint32_t run = wbase + inc - s4;
  {
    uint32_t lo0 = run; run += hw0 & 0xFFFFu;
    uint32_t hi0 = run; run += hw0 >> 16;
    offsw[2 * tid] = lo0 | (hi0 << 16);
    uint32_t lo1 = run; run += hw1 & 0xFFFFu;
    uint32_t hi1 = run; run += hw1 >> 16;
    offsw[2 * tid + 1] = lo1 | (hi1 << 16);
  }
  if (tid == 0) {
    float var = 0.0f;
#pragma unroll
    for (int w = 0; w < 16; ++w) var += sh[48 + w];
    var /= (float)NNEG;
    float sd = sqrtf(var);
    sh[4] = 1.0f / (2.0f * sd * sd);
  }
  __syncthreads();   // B4: offs + inv2s2 ready

  // scatter
#pragma unroll
  for (int e = 0; e < 4; ++e) {
    int b = bucket_of(vv[e]);
    uint32_t old = atomicAdd(&offsw[b >> 1], 1u << ((b & 1) << 4));
    uint32_t sl = (old >> ((b & 1) << 4)) & 0xFFFFu;
    sval[sl] = vv[e];
  }
  __syncthreads();   // B5: scatter done (offsw = bucket ends)

  // bucket-major rank + score: thread owns buckets tid + 1024*m (interleaved
  // for load balance). Bucket order == rank order -> the wave's G loads are
  // contiguous. Tie-break by scatter slot (u2 < u), same as R6.
  const float inv2s2 = sh[4];
  const uint32_t fbase = (uint32_t)row * (uint32_t)NNEG;
  float s0 = -FLT_MAX, s1 = -FLT_MAX, s2 = -FLT_MAX;
  float v0 = 0.0f, v1 = 0.0f, v2 = 0.0f;
#pragma unroll
  for (int m = 0; m < 4; ++m) {
    const int b = tid + 1024 * m;
    const uint32_t shft = (uint32_t)((b & 1) << 4);
    const uint32_t en = (offsw[b >> 1] >> shft) & 0xFFFFu;
    const uint32_t cb = (histw[b >> 1] >> shft) & 0xFFFFu;
    const uint32_t st = en - cb;
    for (uint32_t u = st; u < en; ++u) {
      float v = sval[u];
      if (v < 1e30f) {
        uint32_t rk = st;
        for (uint32_t u2 = st; u2 < en; ++u2) {
          float w = sval[u2];
          rk += (w < v || (w == v && u2 < u)) ? 1u : 0u;
        }
        float g = USE_G ? G[fbase + rk] : gumbel_at(fbase + rk);
        float d = v - mu;
        float sc = d * d * inv2s2 + g;
        INSERT3(sc, v)
      }
    }
  }

  // wave butterfly top-3 merge (registers only)
#pragma unroll
  for (int dlt = 1; dlt < 64; dlt <<= 1) {
    float t0 = __shfl_xor(s0, dlt, 64), u0 = __shfl_xor(v0, dlt, 64);
    float t1 = __shfl_xor(s1, dlt, 64), u1 = __shfl_xor(v1, dlt, 64);
    float t2 = __shfl_xor(s2, dlt, 64), u2 = __shfl_xor(v2, dlt, 64);
    INSERT3(t0, u0)
    INSERT3(t1, u1)
    INSERT3(t2, u2)
  }
  if (lane == 0) {
    int b0 = 64 + wid * 6;
    sh[b0 + 0] = s0; sh[b0 + 1] = v0;
    sh[b0 + 2] = s1; sh[b0 + 3] = v1;
    sh[b0 + 4] = s2; sh[b0 + 5] = v2;
  }
  __syncthreads();   // B6: wave top-3s in sh

  if (tid == 0) {
    float g0 = -FLT_MAX, g1 = -FLT_MAX, g2 = -FLT_MAX;
    float w0 = 0.0f, w1 = 0.0f, w2 = 0.0f;
    {
      float s0 = g0, s1 = g1, s2 = g2, v0 = w0, v1 = w1, v2 = w2;
      for (int i = 0; i < 48; ++i) {
        float sc = sh[64 + 2 * i], v = sh[64 + 2 * i + 1];
        INSERT3(sc, v)
      }
      g0 = s0; g1 = s1; g2 = s2; w0 = v0; w1 = v1; w2 = v2;
    }
    float negmax = fmaxf(w0, fmaxf(w1, w2));
    float neg_loss = 0.04f * (log1pf(expf(50.0f * (w0 - MARGIN))) +
                              log1pf(expf(50.0f * (w1 - MARGIN))) +
                              log1pf(expf(50.0f * (w2 - MARGIN)))) / 3.0f;
    float p0 = sh[0], p1 = sh[1], p2 = sh[2];
    float pos_loss = (log1pf(expf(-2.0f * (p0 - MARGIN))) +
                      log1pf(expf(-2.0f * (p1 - MARGIN))) +
                      log1pf(expf(-2.0f * (p2 - MARGIN)))) / 3.0f;
    atomicAdd(&acc[0], pos_loss + neg_loss);
    if (p2 > negmax + 0.05f) atomicAdd(&acc[1], 1.0f);
    atomicAdd(&acc[2], p0 + p1 + p2);
    atomicAdd(&acc[3], sh[9]);
  }
}

// ---------------------------------------------------------------------------
__global__ void finalize(const float* __restrict__ acc, float* out) {
  if (threadIdx.x == 0 && blockIdx.x == 0) {
    out[0] = acc[0] / 4096.0f;                    // loss
    out[1] = acc[1] / 4096.0f;                    // prec
    out[2] = acc[2] / (4096.0f * 3.0f);           // pos_d
    out[3] = acc[3] / (4096.0f * 4092.0f);        // neg_d
  }
}

extern "C" void kernel_launch(void* const* d_in, const int* in_sizes, int n_in,
                              void* d_out, int out_size, void* d_ws, size_t ws_size,
                              hipStream_t stream) {
  (void)in_sizes; (void)n_in; (void)out_size;
  const float* X = (const float*)d_in[0];
  float* S = (float*)d_ws;                                   // 64 MB sim matrix
  float* acc = (float*)((char*)d_ws + (size_t)NN * NN * 4);  // 4 f32 accumulators
  float* G = (float*)((char*)d_ws + (size_t)NN * NN * 4 + 256);  // 64 MB gumbel table
  const size_t need = (size_t)NN * NN * 4 + 256 + (size_t)GTOTAL * 4;
  const bool have_g = ws_size >= need;

  hipMemsetAsync(acc, 0, 4 * sizeof(float), stream);
  if (have_g) {
    gemm_gumbel<GUMBEL_BLOCKS><<<GUMBEL_BLOCKS + TRI_BLOCKS, 256, 0, stream>>>(X, S, G);
    row_kernel<1><<<NN, 1024, 0, stream>>>(S, G, acc);
  } else {
    gemm_gumbel<0><<<TRI_BLOCKS, 256, 0, stream>>>(X, S, G);
    row_kernel<0><<<NN, 1024, 0, stream>>>(S, G, acc);
  }
  finalize<<<1, 64, 0, stream>>>(acc, (float*)d_out);
}

// Round 5
// 523.623 us; speedup vs baseline: 2.1508x; 2.1508x over previous
//
#include <hip/hip_runtime.h>
#include <hip/hip_bf16.h>
#include <cstdint>
#include <cfloat>
#include <math.h>

// Problem constants (fixed by the reference)
#define NN 4096      // rows
#define DD 256       // embedding dim
#define NNEG 4092    // negatives per row
#define MARGIN 0.5f
#define GTOTAL ((uint32_t)NN * (uint32_t)NNEG)  // 16,760,832 gumbel entries

// ---------------------------------------------------------------------------
// JAX threefry2x32, key = jax.random.key(42) -> (0, 42). Partitionable mode:
// counter (hi=0, lo=i), bits = o0 ^ o1. (verified bit-exact: absmax 0.0)
// ---------------------------------------------------------------------------
__device__ __forceinline__ uint32_t rotl32(uint32_t x, int r) {
  return (x << r) | (x >> (32 - r));
}

__device__ __forceinline__ void threefry2x32_42(uint32_t x0, uint32_t x1,
                                                uint32_t& o0, uint32_t& o1) {
  const uint32_t k0 = 0u, k1 = 42u;
  const uint32_t k2 = k0 ^ k1 ^ 0x1BD11BDAu;
  x0 += k0; x1 += k1;
#define TF_R(r) { x0 += x1; x1 = rotl32(x1, r); x1 ^= x0; }
  TF_R(13) TF_R(15) TF_R(26) TF_R(6)
  x0 += k1; x1 += k2 + 1u;
  TF_R(17) TF_R(29) TF_R(16) TF_R(24)
  x0 += k2; x1 += k0 + 2u;
  TF_R(13) TF_R(15) TF_R(26) TF_R(6)
  x0 += k0; x1 += k1 + 3u;
  TF_R(17) TF_R(29) TF_R(16) TF_R(24)
  x0 += k1; x1 += k2 + 4u;
  TF_R(13) TF_R(15) TF_R(26) TF_R(6)
  x0 += k2; x1 += k0 + 5u;
#undef TF_R
  o0 = x0; o1 = x1;
}

__device__ __forceinline__ float gumbel_at(uint32_t f) {
  uint32_t o0, o1;
  threefry2x32_42(0u, f, o0, o1);
  uint32_t bits = o0 ^ o1;
  uint32_t fb = (bits >> 9) | 0x3F800000u;
  float fl = __uint_as_float(fb) - 1.0f;
  float u = fmaxf(1e-20f, fl + 1e-20f);
  return -logf(-logf(u));   // libm logf kept: bit-exact anchor (absmax 0.0)
}

// Monotone bucket map over [-0.28, 0.28] (sims ~N(0, 1/256)); within-bucket
// order resolved by exact-value scan, so mapping affects speed only.
#define NB 4096
#define NW (NB / 2)
__device__ __forceinline__ int bucket_of(float v) {
  return (int)fminf(fmaxf((v + 0.28f) * 7314.2857f, 0.0f), (float)(NB - 1));
}

// ---------------------------------------------------------------------------
// GEMM v4 (R8): L2-direct, zero LDS. X is 4 MB -> resident in every XCD's
// 4 MB L2, so A/B fragments are read straight from global (A: 4-address
// broadcast loads; B: 16x16B per wave-instr). Removes the per-CU LDS pipe
// bottleneck (R0-R2 staged versions: 16 ds_read_b128 per 256 FMA -> LDS
// 1536 cy vs FMA 1024 cy per CU) and all barriers. 128x128 tile, 8x8 regs.
// Absolute k accumulation order unchanged (k = 0..255 in xyzw groups of 4)
// -> sims bit-exact. Gumbel-fill blocks lead the grid.
// ---------------------------------------------------------------------------
#define BT 128
#define NT (NN / BT)                      // 32
#define GEMM_BLOCKS (NT * (NT + 1) / 2)   // 528
#define GUMBEL_BLOCKS 256

template <int GOFF>
__global__ __launch_bounds__(256) void gemm_gumbel(const float* __restrict__ X,
                                                   float* __restrict__ S,
                                                   float* __restrict__ G) {
  const int tid = threadIdx.x;

  if (GOFF > 0 && (int)blockIdx.x < GOFF) {
    // Gumbel table fill: pure-VALU grid-stride stream, coalesced writes.
    uint32_t i = (uint32_t)blockIdx.x * 256u + (uint32_t)tid;
    const uint32_t stride = (uint32_t)GOFF * 256u;
    for (; i < GTOTAL; i += stride) G[i] = gumbel_at(i);
    return;
  }

  // decode linear upper-triangle index -> (bi, bj), bi <= bj
  int b = (int)blockIdx.x - GOFF, bi = 0;
  while (b >= NT - bi) { b -= NT - bi; bi++; }
  const int bj = bi + b;
  const int rowBase = bi * BT, colBase = bj * BT;

  const int tx = tid & 15, ty = tid >> 4;
  const float* __restrict__ pa = X + (size_t)(rowBase + ty) * DD;
  const float* __restrict__ pb = X + (size_t)(colBase + tx) * DD;

  float acc[8][8] = {};
#pragma unroll 1
  for (int k = 0; k < DD; k += 4) {
    float4 a[8], bb[8];
#pragma unroll
    for (int i = 0; i < 8; ++i)
      a[i] = *(const float4*)(pa + (size_t)(16 * i) * DD + k);
#pragma unroll
    for (int j = 0; j < 8; ++j)
      bb[j] = *(const float4*)(pb + (size_t)(16 * j) * DD + k);
#pragma unroll
    for (int i = 0; i < 8; ++i)
#pragma unroll
      for (int j = 0; j < 8; ++j) {
        acc[i][j] += a[i].x * bb[j].x;
        acc[i][j] += a[i].y * bb[j].y;
        acc[i][j] += a[i].z * bb[j].z;
        acc[i][j] += a[i].w * bb[j].w;
      }
  }

#pragma unroll
  for (int i = 0; i < 8; ++i)
#pragma unroll
    for (int j = 0; j < 8; ++j)
      S[(size_t)(rowBase + ty + 16 * i) * NN + colBase + tx + 16 * j] = acc[i][j];
  if (bi != bj) {
#pragma unroll
    for (int i = 0; i < 8; ++i)
#pragma unroll
      for (int j = 0; j < 8; ++j)
        S[(size_t)(colBase + tx + 16 * j) * NN + rowBase + ty + 16 * i] = acc[i][j];
  }
}

// ---------------------------------------------------------------------------
// Per-row kernel v8: the slot-major v6 algorithm (bit-exact, 207us) at 512
// threads / 8 elems per thread. LDS 33.3 KB -> 4 blocks x 8 waves = 32
// waves/CU (full cap, was 10.4), and every serial per-thread chain halves.
// ---------------------------------------------------------------------------
#define INSERT3(sc, v)                                              \
  if ((sc) > s2) {                                                  \
    if ((sc) > s1) {                                                \
      s2 = s1; v2 = v1;                                             \
      if ((sc) > s0) { s1 = s0; v1 = v0; s0 = (sc); v0 = (v); }     \
      else           { s1 = (sc); v1 = (v); }                       \
    } else { s2 = (sc); v2 = (v); }                                 \
  }

#define RE 8   // elements per thread (512 threads)

template <int USE_G>
__global__ __launch_bounds__(512) void row_kernel(const float* __restrict__ S,
                                                  const float* __restrict__ G,
                                                  float* __restrict__ acc) {
  __shared__ uint32_t histw[NW];            // 2x16-bit counts per word (8 KB)
  __shared__ uint32_t offsw[NW];            // 2x16-bit cursors (8 KB)
  __shared__ __align__(16) float sval[NN];  // values scattered by bucket (16 KB)
  __shared__ float sh[128];  // 0..2 pos sorted, 3 mu, 4 inv2s2, 9 neg sum,
                             // 16..19 raw pos, 32..39 mean partials,
                             // 48..55 var partials, 64..111 wave top-3
  __shared__ uint32_t wtot[8];

  const int row = blockIdx.x;
  const int tid = threadIdx.x;
  const int lane = tid & 63, wid = tid >> 6;

  // zero histogram: 4 words/thread, stride 512 -> conflict-free
#pragma unroll
  for (int i = 0; i < 4; ++i) histw[tid + 512 * i] = 0u;

  // load 8 elements (two coalesced float4), capture + poison positives
  const float4* src = (const float4*)(S + (size_t)row * NN);
  const int pslot = row >> 2;
  float vv[RE];
#pragma unroll
  for (int it = 0; it < 2; ++it) {
    int slot = tid + 512 * it;
    float4 t4 = src[slot];
    if (slot == pslot) {
      sh[16] = t4.x; sh[17] = t4.y; sh[18] = t4.z; sh[19] = t4.w;
      t4.x = INFINITY; t4.y = INFINITY; t4.z = INFINITY; t4.w = INFINITY;
    }
    vv[4 * it + 0] = t4.x; vv[4 * it + 1] = t4.y;
    vv[4 * it + 2] = t4.z; vv[4 * it + 3] = t4.w;
  }

  // mean partial sums (skip infs)
  float s = 0.0f;
#pragma unroll
  for (int e = 0; e < RE; ++e) if (vv[e] < 1e30f) s += vv[e];
#pragma unroll
  for (int off = 32; off > 0; off >>= 1) s += __shfl_down(s, off, 64);
  if (lane == 0) sh[32 + wid] = s;
  __syncthreads();   // B1: hist zeroed, mean partials, raw pos visible

  // histogram (packed halves; counts <= 4096 so no carry between halves)
#pragma unroll
  for (int e = 0; e < RE; ++e) {
    int b = bucket_of(vv[e]);
    atomicAdd(&histw[b >> 1], 1u << ((b & 1) << 4));
  }
  if (tid == 0) {
    int self = row & 3;
    float p[3]; int m = 0;
#pragma unroll
    for (int c = 0; c < 4; ++c)
      if (c != self) p[m++] = sh[16 + c];
    float t;
    if (p[0] > p[1]) { t = p[0]; p[0] = p[1]; p[1] = t; }
    if (p[1] > p[2]) { t = p[1]; p[1] = p[2]; p[2] = t; }
    if (p[0] > p[1]) { t = p[0]; p[0] = p[1]; p[1] = t; }
    sh[0] = p[0]; sh[1] = p[1]; sh[2] = p[2];
    float tot = 0.0f;
#pragma unroll
    for (int w = 0; w < 8; ++w) tot += sh[32 + w];
    sh[9] = tot;
    sh[3] = tot / (float)NNEG;
  }
  __syncthreads();   // B2: hist complete, mu visible

  // block exclusive prefix over NB buckets (8 buckets = 4 words per thread)
  uint32_t hwv[4];
  uint32_t s8 = 0;
#pragma unroll
  for (int j = 0; j < 4; ++j) {
    hwv[j] = histw[4 * tid + j];
    s8 += (hwv[j] & 0xFFFFu) + (hwv[j] >> 16);
  }
  uint32_t inc = s8;
#pragma unroll
  for (int off = 1; off < 64; off <<= 1) {
    uint32_t n = __shfl_up(inc, (unsigned)off, 64);
    if (lane >= off) inc += n;
  }
  if (lane == 63) wtot[wid] = inc;

  // variance partial sums (two-pass; mu from B2)
  const float mu = sh[3];
  float q = 0.0f;
#pragma unroll
  for (int e = 0; e < RE; ++e)
    if (vv[e] < 1e30f) { float d = vv[e] - mu; q += d * d; }
#pragma unroll
  for (int off = 32; off > 0; off >>= 1) q += __shfl_down(q, off, 64);
  if (lane == 0) sh[48 + wid] = q;
  __syncthreads();   // B3: wtot + var partials visible

  uint32_t wbase = 0;
  for (int w = 0; w < wid; ++w) wbase += wtot[w];
  uint32_t run = wbase + inc - s8;
#pragma unroll
  for (int j = 0; j < 4; ++j) {
    uint32_t lo = run; run += hwv[j] & 0xFFFFu;
    uint32_t hi = run; run += hwv[j] >> 16;
    offsw[4 * tid + j] = lo | (hi << 16);
  }
  if (tid == 0) {
    float var = 0.0f;
#pragma unroll
    for (int w = 0; w < 8; ++w) var += sh[48 + w];
    var /= (float)NNEG;
    float sd = sqrtf(var);
    sh[4] = 1.0f / (2.0f * sd * sd);
  }
  __syncthreads();   // B4: offs + inv2s2 ready

  // scatter
#pragma unroll
  for (int e = 0; e < RE; ++e) {
    int b = bucket_of(vv[e]);
    uint32_t old = atomicAdd(&offsw[b >> 1], 1u << ((b & 1) << 4));
    uint32_t sl = (old >> ((b & 1) << 4)) & 0xFFFFu;
    sval[sl] = vv[e];
  }
  __syncthreads();   // B5: scatter done (offsw = bucket ends)

  // rank + score, slot-major. Batched: values, bucket bounds, then 8-wide
  // prefetched b128 scans (address-independent -> pipelined).
  const float inv2s2 = sh[4];
  const uint32_t fbase = (uint32_t)row * (uint32_t)NNEG;
  const float* __restrict__ Grow = G + fbase;
  float s0 = -FLT_MAX, s1 = -FLT_MAX, s2 = -FLT_MAX;
  float v0 = 0.0f, v1 = 0.0f, v2 = 0.0f;

  float va[RE]; uint32_t sten[RE];
#pragma unroll
  for (int it = 0; it < RE; ++it) va[it] = sval[tid + 512 * it];
#pragma unroll
  for (int it = 0; it < RE; ++it) {
    float v = va[it];
    uint32_t pk = 0u;
    if (v < 1e30f) {
      int b = bucket_of(v);
      uint32_t sh16 = (uint32_t)((b & 1) << 4);
      uint32_t end = (offsw[b >> 1] >> sh16) & 0xFFFFu;
      uint32_t cb = (histw[b >> 1] >> sh16) & 0xFFFFu;
      pk = (end - cb) | (end << 16);
    }
    sten[it] = pk;
  }

  float4 w0[RE];
#pragma unroll
  for (int j = 0; j < RE; ++j) {
    uint32_t st = sten[j] & 0xFFFFu;
    w0[j] = *(const float4*)(sval + (st & ~3u));
  }
#pragma unroll
  for (int j = 0; j < RE; ++j) {
    float v = va[j];
    if (v < 1e30f) {
      const int sl = tid + 512 * j;
      const uint32_t st = sten[j] & 0xFFFFu, en = sten[j] >> 16;
      const uint32_t nb = en - st;
      const uint32_t u0 = st & ~3u;
      int cnt = (int)st;
      {
        float4 w = w0[j];
        cnt += ((u0 + 0 - st) < nb && (w.x < v || (w.x == v && (int)(u0 + 0) < sl))) ? 1 : 0;
        cnt += ((u0 + 1 - st) < nb && (w.y < v || (w.y == v && (int)(u0 + 1) < sl))) ? 1 : 0;
        cnt += ((u0 + 2 - st) < nb && (w.z < v || (w.z == v && (int)(u0 + 2) < sl))) ? 1 : 0;
        cnt += ((u0 + 3 - st) < nb && (w.w < v || (w.w == v && (int)(u0 + 3) < sl))) ? 1 : 0;
      }
      for (uint32_t u = u0 + 4; u < en; u += 4) {
        float4 w = *(const float4*)(sval + u);
        cnt += ((u + 0 - st) < nb && (w.x < v || (w.x == v && (int)(u + 0) < sl))) ? 1 : 0;
        cnt += ((u + 1 - st) < nb && (w.y < v || (w.y == v && (int)(u + 1) < sl))) ? 1 : 0;
        cnt += ((u + 2 - st) < nb && (w.z < v || (w.z == v && (int)(u + 2) < sl))) ? 1 : 0;
        cnt += ((u + 3 - st) < nb && (w.w < v || (w.w == v && (int)(u + 3) < sl))) ? 1 : 0;
      }
      float g = USE_G ? Grow[cnt] : gumbel_at(fbase + (uint32_t)cnt);
      float d = v - mu;
      float sc = d * d * inv2s2 + g;
      INSERT3(sc, v)
    }
  }

  // wave butterfly top-3 merge (registers only)
#pragma unroll
  for (int dlt = 1; dlt < 64; dlt <<= 1) {
    float t0 = __shfl_xor(s0, dlt, 64), u0 = __shfl_xor(v0, dlt, 64);
    float t1 = __shfl_xor(s1, dlt, 64), u1 = __shfl_xor(v1, dlt, 64);
    float t2 = __shfl_xor(s2, dlt, 64), u2 = __shfl_xor(v2, dlt, 64);
    INSERT3(t0, u0)
    INSERT3(t1, u1)
    INSERT3(t2, u2)
  }
  if (lane == 0) {
    int b0 = 64 + wid * 6;
    sh[b0 + 0] = s0; sh[b0 + 1] = v0;
    sh[b0 + 2] = s1; sh[b0 + 3] = v1;
    sh[b0 + 4] = s2; sh[b0 + 5] = v2;
  }
  __syncthreads();   // B6: wave top-3s in sh

  if (tid == 0) {
    float g0 = -FLT_MAX, g1 = -FLT_MAX, g2 = -FLT_MAX;
    float w0s = 0.0f, w1s = 0.0f, w2s = 0.0f;
    {
      float s0 = g0, s1 = g1, s2 = g2, v0 = w0s, v1 = w1s, v2 = w2s;
      for (int i = 0; i < 24; ++i) {
        float sc = sh[64 + 2 * i], v = sh[64 + 2 * i + 1];
        INSERT3(sc, v)
      }
      g0 = s0; g1 = s1; g2 = s2; w0s = v0; w1s = v1; w2s = v2;
    }
    float negmax = fmaxf(w0s, fmaxf(w1s, w2s));
    float neg_loss = 0.04f * (log1pf(expf(50.0f * (w0s - MARGIN))) +
                              log1pf(expf(50.0f * (w1s - MARGIN))) +
                              log1pf(expf(50.0f * (w2s - MARGIN)))) / 3.0f;
    float p0 = sh[0], p1 = sh[1], p2 = sh[2];
    float pos_loss = (log1pf(expf(-2.0f * (p0 - MARGIN))) +
                      log1pf(expf(-2.0f * (p1 - MARGIN))) +
                      log1pf(expf(-2.0f * (p2 - MARGIN)))) / 3.0f;
    atomicAdd(&acc[0], pos_loss + neg_loss);
    if (p2 > negmax + 0.05f) atomicAdd(&acc[1], 1.0f);
    atomicAdd(&acc[2], p0 + p1 + p2);
    atomicAdd(&acc[3], sh[9]);
  }
}

// ---------------------------------------------------------------------------
__global__ void finalize(const float* __restrict__ acc, float* out) {
  if (threadIdx.x == 0 && blockIdx.x == 0) {
    out[0] = acc[0] / 4096.0f;                    // loss
    out[1] = acc[1] / 4096.0f;                    // prec
    out[2] = acc[2] / (4096.0f * 3.0f);           // pos_d
    out[3] = acc[3] / (4096.0f * 4092.0f);        // neg_d
  }
}

extern "C" void kernel_launch(void* const* d_in, const int* in_sizes, int n_in,
                              void* d_out, int out_size, void* d_ws, size_t ws_size,
                              hipStream_t stream) {
  (void)in_sizes; (void)n_in; (void)out_size;
  const float* X = (const float*)d_in[0];
  float* S = (float*)d_ws;                                   // 64 MB sim matrix
  float* acc = (float*)((char*)d_ws + (size_t)NN * NN * 4);  // 4 f32 accumulators
  float* G = (float*)((char*)d_ws + (size_t)NN * NN * 4 + 256);  // 64 MB gumbel table
  const size_t need = (size_t)NN * NN * 4 + 256 + (size_t)GTOTAL * 4;
  const bool have_g = ws_size >= need;

  hipMemsetAsync(acc, 0, 4 * sizeof(float), stream);
  if (have_g) {
    gemm_gumbel<GUMBEL_BLOCKS><<<GUMBEL_BLOCKS + GEMM_BLOCKS, 256, 0, stream>>>(X, S, G);
    row_kernel<1><<<NN, 512, 0, stream>>>(S, G, acc);
  } else {
    gemm_gumbel<0><<<GEMM_BLOCKS, 256, 0, stream>>>(X, S, G);
    row_kernel<0><<<NN, 512, 0, stream>>>(S, G, acc);
  }
  finalize<<<1, 64, 0, stream>>>(acc, (float*)d_out);
}

// Round 6
// 403.360 us; speedup vs baseline: 2.7921x; 1.2982x over previous
//
#include <hip/hip_runtime.h>
#include <hip/hip_bf16.h>
#include <cstdint>
#include <cfloat>
#include <math.h>

// Problem constants (fixed by the reference)
#define NN 4096      // rows
#define DD 256       // embedding dim
#define NNEG 4092    // negatives per row
#define MARGIN 0.5f
#define NB 3584      // counting-sort buckets (14 per thread; 2 per LDS word)
#define NW (NB / 2)  // packed words
#define GTOTAL ((uint32_t)NN * (uint32_t)NNEG)  // 16,760,832 gumbel entries

// ---------------------------------------------------------------------------
// JAX threefry2x32, key = jax.random.key(42) -> (0, 42). Partitionable mode:
// counter (hi=0, lo=i), bits = o0 ^ o1. (verified bit-exact: absmax 0.0)
// ---------------------------------------------------------------------------
__device__ __forceinline__ uint32_t rotl32(uint32_t x, int r) {
  return (x << r) | (x >> (32 - r));
}

__device__ __forceinline__ void threefry2x32_42(uint32_t x0, uint32_t x1,
                                                uint32_t& o0, uint32_t& o1) {
  const uint32_t k0 = 0u, k1 = 42u;
  const uint32_t k2 = k0 ^ k1 ^ 0x1BD11BDAu;
  x0 += k0; x1 += k1;
#define TF_R(r) { x0 += x1; x1 = rotl32(x1, r); x1 ^= x0; }
  TF_R(13) TF_R(15) TF_R(26) TF_R(6)
  x0 += k1; x1 += k2 + 1u;
  TF_R(17) TF_R(29) TF_R(16) TF_R(24)
  x0 += k2; x1 += k0 + 2u;
  TF_R(13) TF_R(15) TF_R(26) TF_R(6)
  x0 += k0; x1 += k1 + 3u;
  TF_R(17) TF_R(29) TF_R(16) TF_R(24)
  x0 += k1; x1 += k2 + 4u;
  TF_R(13) TF_R(15) TF_R(26) TF_R(6)
  x0 += k2; x1 += k0 + 5u;
#undef TF_R
  o0 = x0; o1 = x1;
}

__device__ __forceinline__ float gumbel_at(uint32_t f) {
  uint32_t o0, o1;
  threefry2x32_42(0u, f, o0, o1);
  uint32_t bits = o0 ^ o1;
  uint32_t fb = (bits >> 9) | 0x3F800000u;
  float fl = __uint_as_float(fb) - 1.0f;
  float u = fmaxf(1e-20f, fl + 1e-20f);
  return -logf(-logf(u));   // libm logf kept: bit-exact anchor (absmax 0.0)
}

// Monotone bucket map over [-0.28, 0.28] (sims ~N(0, 1/256)); within-bucket
// order resolved by exact-value scan, so mapping affects speed only.
__device__ __forceinline__ int bucket_of(float v) {
  return (int)fminf(fmaxf((v + 0.28f) * 6400.0f, 0.0f), (float)(NB - 1));
}

// ---------------------------------------------------------------------------
// Symmetric GEMM: S = X * X^T (R1's measured-best staged version, ~150us).
// Upper-triangle 128x128 blocks, BK=32, LDS 36.9 KB -> 4 blocks/CU.
// k-accumulation order: k ascending, step 4, .x.y.z.w -> sims bit-exact.
// Gumbel-fill blocks trail the grid (R1 config, measured).
// ---------------------------------------------------------------------------
#define BT 128
#define NT (NN / BT)   // 32 -> 528 upper-triangle blocks
#define BK 32
#define LDSS 36        // padded LDS row stride (dwords)
#define GEMM_BLOCKS (NT * (NT + 1) / 2)   // 528
#define GUMBEL_BLOCKS 240

template <int GOFF>
__global__ __launch_bounds__(256) void gemm_gumbel(const float* __restrict__ X,
                                                   float* __restrict__ S,
                                                   float* __restrict__ G) {
  __shared__ float As[BT * LDSS];
  __shared__ float Bs[BT * LDSS];
  const int tid = threadIdx.x;

  if (GOFF > 0 && (int)blockIdx.x >= GEMM_BLOCKS) {
    // Gumbel table fill: pure-VALU grid-stride stream, coalesced writes.
    uint32_t i = (uint32_t)(blockIdx.x - GEMM_BLOCKS) * 256u + (uint32_t)tid;
    const uint32_t stride = (uint32_t)GOFF * 256u;
    for (; i < GTOTAL; i += stride) G[i] = gumbel_at(i);
    return;
  }

  const int tx = tid & 15, ty = tid >> 4;

  // decode linear upper-triangle index -> (bi, bj), bi <= bj
  int b = blockIdx.x, bi = 0;
  while (b >= NT - bi) { b -= NT - bi; bi++; }
  const int bj = bi + b;
  const int rowBase = bi * BT, colBase = bj * BT;

  float acc[8][8] = {};
  for (int kb = 0; kb < DD; kb += BK) {
#pragma unroll
    for (int it = 0; it < 4; ++it) {
      int idx = tid + 256 * it;            // 1024 float4 slots: 128 rows x 8
      int r = idx >> 3, c4 = idx & 7;
      float4 av = *(const float4*)(X + (size_t)(rowBase + r) * DD + kb + c4 * 4);
      float4 bv = *(const float4*)(X + (size_t)(colBase + r) * DD + kb + c4 * 4);
      *(float4*)(As + r * LDSS + c4 * 4) = av;
      *(float4*)(Bs + r * LDSS + c4 * 4) = bv;
    }
    __syncthreads();
    for (int k = 0; k < BK; k += 4) {
      float4 a[8], bfr[8];
#pragma unroll
      for (int i = 0; i < 8; ++i) a[i] = *(const float4*)(As + (ty + 16 * i) * LDSS + k);
#pragma unroll
      for (int j = 0; j < 8; ++j) bfr[j] = *(const float4*)(Bs + (tx + 16 * j) * LDSS + k);
#pragma unroll
      for (int i = 0; i < 8; ++i)
#pragma unroll
        for (int j = 0; j < 8; ++j) {
          acc[i][j] += a[i].x * bfr[j].x;
          acc[i][j] += a[i].y * bfr[j].y;
          acc[i][j] += a[i].z * bfr[j].z;
          acc[i][j] += a[i].w * bfr[j].w;
        }
    }
    __syncthreads();
  }
#pragma unroll
  for (int i = 0; i < 8; ++i)
#pragma unroll
    for (int j = 0; j < 8; ++j)
      S[(size_t)(rowBase + ty + 16 * i) * NN + colBase + tx + 16 * j] = acc[i][j];
  if (bi != bj) {
#pragma unroll
    for (int i = 0; i < 8; ++i)
#pragma unroll
      for (int j = 0; j < 8; ++j)
        S[(size_t)(colBase + tx + 16 * j) * NN + rowBase + ty + 16 * i] = acc[i][j];
  }
}

// ---------------------------------------------------------------------------
// Per-row kernel v9: identical algorithm to the measured v6 (208us, absmax 0)
// but the 16 KB sval scratch moves to a private per-row GLOBAL region
// (GSV=1). LDS drops 31 -> ~14.6 KB: blocks/CU 2.6 -> ~8, waves 10.6 -> 32.
// Scatter->scan visibility via __syncthreads (same block, write-first region,
// region never read before the scatter). GSV=0 keeps the verified LDS path.
// ---------------------------------------------------------------------------
#define INSERT3(sc, v)                                              \
  if ((sc) > s2) {                                                  \
    if ((sc) > s1) {                                                \
      s2 = s1; v2 = v1;                                             \
      if ((sc) > s0) { s1 = s0; v1 = v0; s0 = (sc); v0 = (v); }     \
      else           { s1 = (sc); v1 = (v); }                       \
    } else { s2 = (sc); v2 = (v); }                                 \
  }

template <int USE_G, int GSV>
__global__ __launch_bounds__(256) void row_kernel(const float* __restrict__ S,
                                                  const float* __restrict__ G,
                                                  float* __restrict__ svg,
                                                  float* __restrict__ acc) {
  __shared__ uint32_t histw[NW];  // 2x16-bit counts per word (7 KB)
  __shared__ uint32_t offsw[NW];  // 2x16-bit cursors -> bucket ends (7 KB)
  __shared__ __align__(16) float svs[GSV ? 4 : NN];  // LDS fallback scratch
  __shared__ float sh[48];        // 0..2 pos sorted, 3 mu, 4 inv2s2,
                                  // 5..8 mean partials, 9 neg sum,
                                  // 10..13 var partials, 16..19 raw pos,
                                  // 24..47 wave top-3 (s,v)x3x4
  __shared__ uint32_t wtot[4];

  const int row = blockIdx.x;
  const int tid = threadIdx.x;
  const int lane = tid & 63, wid = tid >> 6;

  float* __restrict__ sv = GSV ? (svg + ((size_t)row << 12)) : svs;

  // zero histogram: 7 words/thread, stride 256 -> conflict-free
#pragma unroll
  for (int i = 0; i < 7; ++i) histw[tid + 256 * i] = 0u;

  // load 16 elements (coalesced float4), capture positives, poison class block
  const float4* src = (const float4*)(S + (size_t)row * NN);
  const int pslot = row >> 2;
  float vv[16];
#pragma unroll
  for (int it = 0; it < 4; ++it) {
    int slot = tid + 256 * it;
    float4 t4 = src[slot];
    if (slot == pslot) {
      sh[16] = t4.x; sh[17] = t4.y; sh[18] = t4.z; sh[19] = t4.w;
      t4.x = INFINITY; t4.y = INFINITY; t4.z = INFINITY; t4.w = INFINITY;
    }
    vv[4 * it + 0] = t4.x; vv[4 * it + 1] = t4.y;
    vv[4 * it + 2] = t4.z; vv[4 * it + 3] = t4.w;
  }

  // mean partial sums (skip infs)
  float s = 0.0f;
#pragma unroll
  for (int e = 0; e < 16; ++e) if (vv[e] < 1e30f) s += vv[e];
#pragma unroll
  for (int off = 32; off > 0; off >>= 1) s += __shfl_down(s, off, 64);
  if (lane == 0) sh[5 + wid] = s;
  __syncthreads();   // B1: hist zeroed, mean partials, raw pos visible

  // histogram (packed halves; counts <= 4096 so no carry between halves)
#pragma unroll
  for (int e = 0; e < 16; ++e) {
    int b = bucket_of(vv[e]);
    atomicAdd(&histw[b >> 1], 1u << ((b & 1) << 4));
  }
  if (tid == 0) {
    int self = row & 3;
    float p[3]; int m = 0;
#pragma unroll
    for (int c = 0; c < 4; ++c)
      if (c != self) p[m++] = sh[16 + c];
    float t;
    if (p[0] > p[1]) { t = p[0]; p[0] = p[1]; p[1] = t; }
    if (p[1] > p[2]) { t = p[1]; p[1] = p[2]; p[2] = t; }
    if (p[0] > p[1]) { t = p[0]; p[0] = p[1]; p[1] = t; }
    sh[0] = p[0]; sh[1] = p[1]; sh[2] = p[2];
    float tot = sh[5] + sh[6] + sh[7] + sh[8];
    sh[9] = tot;
    sh[3] = tot / (float)NNEG;
  }
  __syncthreads();   // B2: hist complete, mu visible

  // block exclusive prefix over NB buckets (14 buckets = 7 words per thread)
  uint32_t hw[7];
  uint32_t s14 = 0;
#pragma unroll
  for (int j = 0; j < 7; ++j) {
    hw[j] = histw[7 * tid + j];
    s14 += (hw[j] & 0xFFFFu) + (hw[j] >> 16);
  }
  uint32_t inc = s14;
#pragma unroll
  for (int off = 1; off < 64; off <<= 1) {
    uint32_t n = __shfl_up(inc, (unsigned)off, 64);
    if (lane >= off) inc += n;
  }
  if (lane == 63) wtot[wid] = inc;

  // variance partial sums (two-pass; mu from B2)
  const float mu = sh[3];
  float q = 0.0f;
#pragma unroll
  for (int e = 0; e < 16; ++e)
    if (vv[e] < 1e30f) { float d = vv[e] - mu; q += d * d; }
#pragma unroll
  for (int off = 32; off > 0; off >>= 1) q += __shfl_down(q, off, 64);
  if (lane == 0) sh[10 + wid] = q;
  __syncthreads();   // B3: wtot + var partials visible

  uint32_t wbase = 0;
  for (int w = 0; w < wid; ++w) wbase += wtot[w];
  uint32_t run = wbase + inc - s14;
#pragma unroll
  for (int j = 0; j < 7; ++j) {
    uint32_t lo = run; run += hw[j] & 0xFFFFu;
    uint32_t hi = run; run += hw[j] >> 16;
    offsw[7 * tid + j] = lo | (hi << 16);
  }
  if (tid == 0) {
    float var = (sh[10] + sh[11] + sh[12] + sh[13]) / (float)NNEG;
    float sd = sqrtf(var);
    sh[4] = 1.0f / (2.0f * sd * sd);
  }
  __syncthreads();   // B4: offs + inv2s2 ready

  // scatter (LDS cursors; values to sv = global region when GSV)
#pragma unroll
  for (int e = 0; e < 16; ++e) {
    int b = bucket_of(vv[e]);
    uint32_t old = atomicAdd(&offsw[b >> 1], 1u << ((b & 1) << 4));
    uint32_t sl = (old >> ((b & 1) << 4)) & 0xFFFFu;
    sv[sl] = vv[e];
  }
  __syncthreads();   // B5: scatter done (offsw = bucket ends)

  // rank + score, slot-major. Batched: values, then bucket bounds, then
  // 8-wide prefetched float4 scans (address-independent -> pipelined).
  const float inv2s2 = sh[4];
  const uint32_t fbase = (uint32_t)row * (uint32_t)NNEG;
  const float* __restrict__ Grow = G + fbase;
  float s0 = -FLT_MAX, s1 = -FLT_MAX, s2 = -FLT_MAX;
  float v0 = 0.0f, v1 = 0.0f, v2 = 0.0f;

  float va[16]; uint32_t sten[16];
#pragma unroll
  for (int it = 0; it < 16; ++it) va[it] = sv[tid + 256 * it];
#pragma unroll
  for (int it = 0; it < 16; ++it) {
    float v = va[it];
    uint32_t pk = 0u;
    if (v < 1e30f) {
      int b = bucket_of(v);
      uint32_t sh16 = (uint32_t)((b & 1) << 4);
      uint32_t end = (offsw[b >> 1] >> sh16) & 0xFFFFu;
      uint32_t cb = (histw[b >> 1] >> sh16) & 0xFFFFu;
      pk = (end - cb) | (end << 16);
    }
    sten[it] = pk;
  }

#pragma unroll
  for (int half = 0; half < 2; ++half) {
    float4 w0[8];
#pragma unroll
    for (int j = 0; j < 8; ++j) {
      uint32_t st = sten[half * 8 + j] & 0xFFFFu;
      w0[j] = *(const float4*)(sv + (st & ~3u));
    }
#pragma unroll
    for (int j = 0; j < 8; ++j) {
      const int it = half * 8 + j;
      float v = va[it];
      if (v < 1e30f) {
        const int sl = tid + 256 * it;
        const uint32_t st = sten[it] & 0xFFFFu, en = sten[it] >> 16;
        const uint32_t nb = en - st;
        const uint32_t u0 = st & ~3u;
        int cnt = (int)st;
        {
          float4 w = w0[j];
          cnt += ((u0 + 0 - st) < nb && (w.x < v || (w.x == v && (int)(u0 + 0) < sl))) ? 1 : 0;
          cnt += ((u0 + 1 - st) < nb && (w.y < v || (w.y == v && (int)(u0 + 1) < sl))) ? 1 : 0;
          cnt += ((u0 + 2 - st) < nb && (w.z < v || (w.z == v && (int)(u0 + 2) < sl))) ? 1 : 0;
          cnt += ((u0 + 3 - st) < nb && (w.w < v || (w.w == v && (int)(u0 + 3) < sl))) ? 1 : 0;
        }
        for (uint32_t u = u0 + 4; u < en; u += 4) {
          float4 w = *(const float4*)(sv + u);
          cnt += ((u + 0 - st) < nb && (w.x < v || (w.x == v && (int)(u + 0) < sl))) ? 1 : 0;
          cnt += ((u + 1 - st) < nb && (w.y < v || (w.y == v && (int)(u + 1) < sl))) ? 1 : 0;
          cnt += ((u + 2 - st) < nb && (w.z < v || (w.z == v && (int)(u + 2) < sl))) ? 1 : 0;
          cnt += ((u + 3 - st) < nb && (w.w < v || (w.w == v && (int)(u + 3) < sl))) ? 1 : 0;
        }
        float g = USE_G ? Grow[cnt] : gumbel_at(fbase + (uint32_t)cnt);
        float d = v - mu;
        float sc = d * d * inv2s2 + g;
        INSERT3(sc, v)
      }
    }
  }

  // wave butterfly top-3 merge (registers only)
#pragma unroll
  for (int dlt = 1; dlt < 64; dlt <<= 1) {
    float t0 = __shfl_xor(s0, dlt, 64), u0 = __shfl_xor(v0, dlt, 64);
    float t1 = __shfl_xor(s1, dlt, 64), u1 = __shfl_xor(v1, dlt, 64);
    float t2 = __shfl_xor(s2, dlt, 64), u2 = __shfl_xor(v2, dlt, 64);
    INSERT3(t0, u0)
    INSERT3(t1, u1)
    INSERT3(t2, u2)
  }
  if (lane == 0) {
    int b0 = 24 + wid * 6;
    sh[b0 + 0] = s0; sh[b0 + 1] = v0;
    sh[b0 + 2] = s1; sh[b0 + 3] = v1;
    sh[b0 + 4] = s2; sh[b0 + 5] = v2;
  }
  __syncthreads();   // B6: wave top-3s in sh

  if (tid == 0) {
    float g0 = -FLT_MAX, g1 = -FLT_MAX, g2 = -FLT_MAX;
    float w0 = 0.0f, w1 = 0.0f, w2 = 0.0f;
    {
      float s0 = g0, s1 = g1, s2 = g2, v0 = w0, v1 = w1, v2 = w2;
#pragma unroll
      for (int i = 0; i < 12; ++i) {
        float sc = sh[24 + 2 * i], v = sh[24 + 2 * i + 1];
        INSERT3(sc, v)
      }
      g0 = s0; g1 = s1; g2 = s2; w0 = v0; w1 = v1; w2 = v2;
    }
    float negmax = fmaxf(w0, fmaxf(w1, w2));
    float neg_loss = 0.04f * (log1pf(expf(50.0f * (w0 - MARGIN))) +
                              log1pf(expf(50.0f * (w1 - MARGIN))) +
                              log1pf(expf(50.0f * (w2 - MARGIN)))) / 3.0f;
    float p0 = sh[0], p1 = sh[1], p2 = sh[2];
    float pos_loss = (log1pf(expf(-2.0f * (p0 - MARGIN))) +
                      log1pf(expf(-2.0f * (p1 - MARGIN))) +
                      log1pf(expf(-2.0f * (p2 - MARGIN)))) / 3.0f;
    atomicAdd(&acc[0], pos_loss + neg_loss);
    if (p2 > negmax + 0.05f) atomicAdd(&acc[1], 1.0f);
    atomicAdd(&acc[2], p0 + p1 + p2);
    atomicAdd(&acc[3], sh[9]);
  }
}

// ---------------------------------------------------------------------------
__global__ void finalize(const float* __restrict__ acc, float* out) {
  if (threadIdx.x == 0 && blockIdx.x == 0) {
    out[0] = acc[0] / 4096.0f;                    // loss
    out[1] = acc[1] / 4096.0f;                    // prec
    out[2] = acc[2] / (4096.0f * 3.0f);           // pos_d
    out[3] = acc[3] / (4096.0f * 4092.0f);        // neg_d
  }
}

extern "C" void kernel_launch(void* const* d_in, const int* in_sizes, int n_in,
                              void* d_out, int out_size, void* d_ws, size_t ws_size,
                              hipStream_t stream) {
  (void)in_sizes; (void)n_in; (void)out_size;
  const float* X = (const float*)d_in[0];
  float* S = (float*)d_ws;                                       // 64 MB sim matrix
  float* acc = (float*)((char*)d_ws + (size_t)NN * NN * 4);      // 4 f32 accumulators
  float* G = (float*)((char*)d_ws + (size_t)NN * NN * 4 + 256);  // 64 MB gumbel table
  float* SV = (float*)((char*)d_ws + 2 * (size_t)NN * NN * 4 + 256);  // 64 MB scatter scratch
  const size_t need_g = (size_t)NN * NN * 4 + 256 + (size_t)GTOTAL * 4;
  const size_t need_sv = 2 * (size_t)NN * NN * 4 + 256 + (size_t)NN * NN * 4;
  const bool have_g = ws_size >= need_g;
  const bool have_sv = ws_size >= need_sv;

  hipMemsetAsync(acc, 0, 4 * sizeof(float), stream);
  if (have_g) {
    gemm_gumbel<GUMBEL_BLOCKS><<<GEMM_BLOCKS + GUMBEL_BLOCKS, 256, 0, stream>>>(X, S, G);
    if (have_sv) row_kernel<1, 1><<<NN, 256, 0, stream>>>(S, G, SV, acc);
    else         row_kernel<1, 0><<<NN, 256, 0, stream>>>(S, G, SV, acc);
  } else {
    gemm_gumbel<0><<<GEMM_BLOCKS, 256, 0, stream>>>(X, S, G);
    row_kernel<0, 0><<<NN, 256, 0, stream>>>(S, G, SV, acc);
  }
  finalize<<<1, 64, 0, stream>>>(acc, (float*)d_out);
}